// Round 9
// baseline (945.454 us; speedup 1.0000x reference)
//
#include <hip/hip_runtime.h>
#include <math.h>

// Problem constants (from reference)
#define T_TOK 16384
#define DIM   768
#define HID   3072
#define NE    5
#define MT    65            // 128-row m-tiles per expert bucket (cap 8320 rows)
#define HCAP  (MT * 128)
#define MT2   33            // 256-row m-groups covering HCAP (edge guarded)
#define CSTR  32            // counts stride (ints) -> one 128B line per expert
#define EPSF  2.2204460492503131e-16f
#define NXCD  8

typedef short bf16x8  __attribute__((ext_vector_type(8)));   // 8 bf16 in 4 VGPRs
typedef float f32x4   __attribute__((ext_vector_type(4)));
typedef float f32x16  __attribute__((ext_vector_type(16)));

#define MFMA16(A, B, C) __builtin_amdgcn_mfma_f32_16x16x32_bf16((A), (B), (C), 0, 0, 0)
#define MFMA32(A, B, C) __builtin_amdgcn_mfma_f32_32x32x16_bf16((A), (B), (C), 0, 0, 0)

__device__ __forceinline__ unsigned short f2bf(float f) {
    unsigned int u = __float_as_uint(f);
    unsigned int r = (u + 0x7fffu + ((u >> 16) & 1u)) >> 16;  // RNE
    return (unsigned short)r;
}

__device__ __forceinline__ void gld16(const void* g, void* l) {
    __builtin_amdgcn_global_load_lds(
        (const __attribute__((address_space(1))) void*)g,
        (__attribute__((address_space(3))) void*)l, 16, 0, 0);
}

// ---------------- prep: W1 -> LDS-tile-linear, XOR-swizzled bf16 ----------------
// tile t = (e*24 + nb)*12 + kb ; W1p[t*8192 + n*64 + p*8 + j] =
//   bf16( W1[e][ kb*64 + (p^(n&7))*8 + j ][ nb*128 + n ] )
__global__ void prep_w1p(const float* __restrict__ W1, unsigned short* __restrict__ W1p) {
    int idx = blockIdx.x * 256 + threadIdx.x;
    if (idx >= NE * 24 * 12 * 128 * 8) return;
    int p = idx & 7;
    int n = (idx >> 3) & 127;
    int t = idx >> 10;
    int kb = t % 12; t /= 12;
    int nb = t % 24; int e = t / 24;
    int klog = kb * 64 + (p ^ (n & 7)) * 8;
    const float* src = W1 + ((size_t)e * DIM + klog) * HID + nb * 128 + n;
    bf16x8 v;
    #pragma unroll
    for (int j = 0; j < 8; ++j) v[j] = (short)f2bf(src[(size_t)j * HID]);
    *reinterpret_cast<bf16x8*>(W1p + (size_t)idx * 8) = v;
}

// tile t = (e*6 + nb)*48 + kb ; W2p[t*8192 + n*64 + p*8 + j] =
//   bf16( W2[e][ kb*64 + (p^(n&7))*8 + j ][ nb*128 + n ] )
__global__ void prep_w2p(const float* __restrict__ W2, unsigned short* __restrict__ W2p) {
    int idx = blockIdx.x * 256 + threadIdx.x;
    if (idx >= NE * 6 * 48 * 128 * 8) return;
    int p = idx & 7;
    int n = (idx >> 3) & 127;
    int t = idx >> 10;
    int kb = t % 48; t /= 48;
    int nb = t % 6; int e = t / 6;
    int klog = kb * 64 + (p ^ (n & 7)) * 8;
    const float* src = W2 + ((size_t)e * HID + klog) * DIM + nb * 128 + n;
    bf16x8 v;
    #pragma unroll
    for (int j = 0; j < 8; ++j) v[j] = (short)f2bf(src[(size_t)j * DIM]);
    *reinterpret_cast<bf16x8*>(W2p + (size_t)idx * 8) = v;
}

// ---------------- gating + x cast, block-aggregated scatter ----------------
__global__ __launch_bounds__(256) void gate_kernel(
    const float* __restrict__ x, const float* __restrict__ wg,
    unsigned short* __restrict__ xb, int* __restrict__ counts,
    int* __restrict__ btok, float* __restrict__ bgate) {
    __shared__ int   s_e[2][64];
    __shared__ float s_g[2][64];
    __shared__ int   lcnt[NE];
    __shared__ int   gbase[NE];

    const int tid = threadIdx.x;
    if (tid < NE) lcnt[tid] = 0;
    const int grp = tid >> 4, l16 = tid & 15;
    const int t0 = blockIdx.x * 64 + grp * 4;   // 4 consecutive tokens per group

    double acc[4][NE];
    #pragma unroll
    for (int tt = 0; tt < 4; ++tt)
        #pragma unroll
        for (int e = 0; e < NE; ++e) acc[tt][e] = 0.0;

    for (int i = 0; i < 12; ++i) {
        const int dbase = i * 64 + l16 * 4;
        float4 xv[4];
        #pragma unroll
        for (int tt = 0; tt < 4; ++tt) {
            xv[tt] = *reinterpret_cast<const float4*>(x + (size_t)(t0 + tt) * DIM + dbase);
            ushort4 o;
            o.x = f2bf(xv[tt].x); o.y = f2bf(xv[tt].y);
            o.z = f2bf(xv[tt].z); o.w = f2bf(xv[tt].w);
            *reinterpret_cast<ushort4*>(xb + (size_t)(t0 + tt) * DIM + dbase) = o;
        }
        #pragma unroll
        for (int j = 0; j < 4; ++j) {
            const int d = dbase + j;
            float w0 = wg[d * NE + 0], w1 = wg[d * NE + 1], w2 = wg[d * NE + 2];
            float w3 = wg[d * NE + 3], w4 = wg[d * NE + 4];
            #pragma unroll
            for (int tt = 0; tt < 4; ++tt) {
                double xd = (double)((&xv[tt].x)[j]);
                acc[tt][0] += xd * (double)w0;
                acc[tt][1] += xd * (double)w1;
                acc[tt][2] += xd * (double)w2;
                acc[tt][3] += xd * (double)w3;
                acc[tt][4] += xd * (double)w4;
            }
        }
    }
    #pragma unroll
    for (int off = 8; off; off >>= 1)
        #pragma unroll
        for (int tt = 0; tt < 4; ++tt)
            #pragma unroll
            for (int e = 0; e < NE; ++e)
                acc[tt][e] += __shfl_down(acc[tt][e], off, 16);

    if (l16 == 0) {
        #pragma unroll
        for (int tt = 0; tt < 4; ++tt) {
            double v[NE] = {acc[tt][0], acc[tt][1], acc[tt][2], acc[tt][3], acc[tt][4]};
            int i0 = 0;
            for (int e = 1; e < NE; ++e) if (v[e] > v[i0]) i0 = e;
            int i1 = -1;
            for (int e = 0; e < NE; ++e) {
                if (e == i0) continue;
                if (i1 < 0 || v[e] > v[i1]) i1 = e;
            }
            float e1 = expf((float)(v[i1] - v[i0]));
            float g0 = 1.0f / (1.0f + e1);
            int li = grp * 4 + tt;
            s_e[0][li] = i0;  s_g[0][li] = g0;
            s_e[1][li] = i1;  s_g[1][li] = e1 * g0;
        }
    }
    __syncthreads();

    int mye = 0, myoff = 0, mytok = 0;
    float myg = 0.0f;
    if (tid < 128) {
        int li = tid >> 1, which = tid & 1;
        mye = s_e[which][li];
        myg = s_g[which][li];
        mytok = blockIdx.x * 64 + li;
        myoff = atomicAdd(&lcnt[mye], 1);
    }
    __syncthreads();
    if (tid < NE) gbase[tid] = atomicAdd(&counts[tid * CSTR], lcnt[tid]);
    __syncthreads();
    if (tid < 128) {
        int p = gbase[mye] + myoff;
        btok[mye * T_TOK + p] = mytok;
        bgate[mye * T_TOK + p] = myg;
    }
}

// ---------------- combo GEMM: 256x128 tile, BK=64, 8 waves, 3 blocks/CU ----------
// Halves block count vs the 128x128 kernel (per-block fixed cost amortized 2x).
// Wave tile stays 64x64 (wm=wv>>1 in [0,4), wn=wv&1) -> identical fragment/swizzle
// math. As 32KB (single-buffered) + Bs 16KB + sst/ssg 2KB = 50KB -> 3 blocks/CU.
// Sync skeleton = proven round-3 2-barrier loop. XCD-chunked decode retained.
__global__ __launch_bounds__(512, 4) void combo_w(
    const unsigned short* __restrict__ xb,
    const unsigned short* __restrict__ W1p,
    const unsigned short* __restrict__ W2p,
    const float* __restrict__ b1, const float* __restrict__ b2,
    const int* __restrict__ counts, const int* __restrict__ btok,
    const float* __restrict__ bgate,
    unsigned short* __restrict__ h0, unsigned short* __restrict__ h1,
    float* __restrict__ out, int g1e, int g2e) {
    __shared__ __align__(16) unsigned short As[256 * 64];   // 32 KB
    __shared__ __align__(16) unsigned short Bs[128 * 64];   // 16 KB
    __shared__ int   sst[256];
    __shared__ float ssg[256];

    // ---- XCD-chunked, long-job-first decode (256-row m-groups, MT2=33) ----
    const int x = blockIdx.x & 7;        // XCD id (HW round-robins consecutive bx)
    const int i = blockIdx.x >> 3;       // per-XCD job index
    const int NG2 = (g2e >= 0) ? MT2 : 0;
    const int NG1 = (g1e >= 0) ? MT2 : 0;
    const int n2x = (x < NG2) ? (((NG2 - 1 - x) >> 3) + 1) : 0;
    const int n1x = (x < NG1) ? (((NG1 - 1 - x) >> 3) + 1) : 0;
    bool isG2; int e, mt, nt;
    if (i < n2x * 6) {
        isG2 = true;  e = g2e; mt = x + 8 * (i / 6);  nt = i % 6;
    } else {
        int ii = i - n2x * 6;
        if (ii >= n1x * 24) return;      // padded block
        isG2 = false; e = g1e; mt = x + 8 * (ii / 24); nt = ii % 24;
    }
    const int cnt = counts[e * CSTR];
    const int m0 = mt * 256;
    if (m0 >= cnt) return;
    unsigned short* hbuf = (e & 1) ? h1 : h0;  // parity ping-pong (g1e=g2e+1 -> disjoint)

    const int tid = threadIdx.x;
    const int wv = tid >> 6, lane = tid & 63;
    const int wm = wv >> 1, wn = wv & 1;       // 4M x 2N waves; wave tile 64x64
    const int col = lane & 15, quad = lane >> 4;
    const int l8 = lane & 7, r8 = lane >> 3;

    const int ksteps = isG2 ? 48 : 12;

    // A staging: wave wv stages rows [wv*32, wv*32+32), 4 gld16 of 8 rows each
    const unsigned short* aptr[4];
    if (isG2) {
        if (tid < 256) {
            int pos = m0 + tid;
            sst[tid] = (pos < cnt) ? btok[e * T_TOK + pos] : 0;
            ssg[tid] = (pos < cnt) ? bgate[e * T_TOK + pos] : 0.0f;
        }
        #pragma unroll
        for (int q = 0; q < 4; ++q) {
            int row = m0 + wv * 32 + q * 8 + r8;
            if (row > HCAP - 1) row = HCAP - 1;          // h-buffer edge guard
            aptr[q] = hbuf + (size_t)row * HID + (l8 ^ r8) * 8;
        }
    } else {
        #pragma unroll
        for (int q = 0; q < 4; ++q) {
            int r = wv * 32 + q * 8 + r8;
            int pos = m0 + r;
            int tok = btok[e * T_TOK + (pos < cnt ? pos : 0)];
            aptr[q] = xb + (size_t)tok * DIM + (l8 ^ r8) * 8;
        }
    }
    // B staging: wave wv stages Bs n-rows [wv*16, wv*16+16), 2 gld16 of 8 rows
    const unsigned short* btile = isG2
        ? W2p + ((size_t)(e * 6 + nt)) * 48 * 8192
        : W1p + ((size_t)(e * 24 + nt)) * 12 * 8192;

    f32x4 acc[4][4];
    #pragma unroll
    for (int i2 = 0; i2 < 4; ++i2)
        #pragma unroll
        for (int j = 0; j < 4; ++j)
            acc[i2][j] = (f32x4){0.f, 0.f, 0.f, 0.f};

    for (int ks = 0; ks < ksteps; ++ks) {
        const unsigned short* bk =
            btile + (size_t)ks * 8192 + (size_t)(wv * 2) * 512 + lane * 8;
        #pragma unroll
        for (int q = 0; q < 4; ++q)
            gld16(aptr[q] + (size_t)ks * 64, &As[(wv * 4 + q) * 512]);
        #pragma unroll
        for (int q = 0; q < 2; ++q)
            gld16(bk + q * 512, &Bs[(wv * 2 + q) * 512]);
        __syncthreads();
        #pragma unroll
        for (int kf = 0; kf < 2; ++kf) {
            const int p = ((kf * 4 + quad) ^ l8) * 8;
            bf16x8 a[4], b[4];
            #pragma unroll
            for (int i2 = 0; i2 < 4; ++i2)
                a[i2] = *reinterpret_cast<const bf16x8*>(&As[(wm * 64 + i2 * 16 + col) * 64 + p]);
            #pragma unroll
            for (int i2 = 0; i2 < 4; ++i2)
                b[i2] = *reinterpret_cast<const bf16x8*>(&Bs[(wn * 64 + i2 * 16 + col) * 64 + p]);
            #pragma unroll
            for (int i2 = 0; i2 < 4; ++i2)
                #pragma unroll
                for (int j = 0; j < 4; ++j)
                    acc[i2][j] = MFMA16(a[i2], b[j], acc[i2][j]);
        }
        __syncthreads();
    }

    const int nb0 = nt * 128 + wn * 64;
    if (!isG2) {
        #pragma unroll
        for (int j = 0; j < 4; ++j) {
            float bias = b1[e * HID + nb0 + j * 16 + col];
            #pragma unroll
            for (int i2 = 0; i2 < 4; ++i2) {
                #pragma unroll
                for (int r = 0; r < 4; ++r) {
                    int row = m0 + wm * 64 + i2 * 16 + quad * 4 + r;
                    if (row < HCAP) {
                        float v = acc[i2][j][r] + bias;
                        float gl = 0.5f * v * (1.0f + erff(v * 0.70710678118654752f));
                        hbuf[(size_t)row * HID + nb0 + j * 16 + col] = f2bf(gl);
                    }
                }
            }
        }
    } else {
        #pragma unroll
        for (int j = 0; j < 4; ++j) {
            float bias = b2[e * DIM + nb0 + j * 16 + col];
            #pragma unroll
            for (int i2 = 0; i2 < 4; ++i2) {
                #pragma unroll
                for (int r = 0; r < 4; ++r) {
                    int lrow = wm * 64 + i2 * 16 + quad * 4 + r;
                    float g = ssg[lrow];
                    if (g > 0.0f) {
                        float v = acc[i2][j][r] + bias;
                        atomicAdd(out + (size_t)sst[lrow] * DIM + nb0 + j * 16 + col,
                                  g * expf(v));
                    }
                }
            }
        }
    }
}

// ---------------- final: out = log(acc), eps guard (float4) ----------------
__global__ void log_kernel(float* __restrict__ out, int n4) {
    int i = blockIdx.x * 256 + threadIdx.x;
    if (i < n4) {
        float4 v = reinterpret_cast<float4*>(out)[i];
        v.x = logf(v.x == 0.0f ? EPSF : v.x);
        v.y = logf(v.y == 0.0f ? EPSF : v.y);
        v.z = logf(v.z == 0.0f ? EPSF : v.z);
        v.w = logf(v.w == 0.0f ? EPSF : v.w);
        reinterpret_cast<float4*>(out)[i] = v;
    }
}

// ================= fallback path (used only if ws too small) =================
__global__ void prep_w1_v2(const float* __restrict__ W1, unsigned short* __restrict__ W1s) {
    int g = blockIdx.x * 4 + (threadIdx.x >> 6);
    int lane = threadIdx.x & 63;
    int kf = g % 48;
    int rest = g / 48;
    int nt2 = rest % 96;
    int e = rest / 96;
    int n = nt2 * 32 + (lane & 31);
    int k0 = kf * 16 + (lane >> 5) * 8;
    const float* src = W1 + ((size_t)e * DIM + k0) * HID + n;
    bf16x8 v;
    #pragma unroll
    for (int j = 0; j < 8; ++j) v[j] = (short)f2bf(src[(size_t)j * HID]);
    *reinterpret_cast<bf16x8*>(W1s + ((size_t)g * 64 + lane) * 8) = v;
}

__global__ void prep_w2_v2(const float* __restrict__ W2, unsigned short* __restrict__ W2s) {
    int g = blockIdx.x * 4 + (threadIdx.x >> 6);
    int lane = threadIdx.x & 63;
    int kf = g % 192;
    int rest = g / 192;
    int nt2 = rest % 24;
    int e = rest / 24;
    int n = nt2 * 32 + (lane & 31);
    int k0 = kf * 16 + (lane >> 5) * 8;
    const float* src = W2 + ((size_t)e * HID + k0) * DIM + n;
    bf16x8 v;
    #pragma unroll
    for (int j = 0; j < 8; ++j) v[j] = (short)f2bf(src[(size_t)j * DIM]);
    *reinterpret_cast<bf16x8*>(W2s + ((size_t)g * 64 + lane) * 8) = v;
}

__global__ __launch_bounds__(512, 2) void expert_v2(
    const unsigned short* __restrict__ xb, const unsigned short* __restrict__ W1s,
    const unsigned short* __restrict__ W2s, const float* __restrict__ b1,
    const float* __restrict__ b2, const int* __restrict__ counts,
    const int* __restrict__ btok, const float* __restrict__ bgate,
    float* __restrict__ out) {
    __shared__ __align__(16) unsigned short xs[64][776];
    __shared__ __align__(16) unsigned short hs[2][64][136];
    __shared__ int   st[64];
    __shared__ float sg[64];

    const int e = blockIdx.y;
    const int cnt = counts[e * CSTR];
    const int m0 = blockIdx.x * 64;
    if (m0 >= cnt) return;

    const int tid = threadIdx.x;
    const int wv = tid >> 6, lane = tid & 63;
    const int l31 = lane & 31, lhi = lane >> 5;

    if (tid < 64) {
        int pos = m0 + tid;
        st[tid] = (pos < cnt) ? btok[e * T_TOK + pos] : 0;
        sg[tid] = (pos < cnt) ? bgate[e * T_TOK + pos] : 0.0f;
    }
    __syncthreads();
    {
        int r = tid >> 3, seg = tid & 7;
        const unsigned short* src = xb + (size_t)st[r] * DIM + seg * 96;
        unsigned short* dst = &xs[r][seg * 96];
        #pragma unroll
        for (int i = 0; i < 12; ++i)
            reinterpret_cast<bf16x8*>(dst)[i] = reinterpret_cast<const bf16x8*>(src)[i];
    }
    __syncthreads();

    const int mt2 = wv & 1, nt2l = wv >> 1;
    f32x16 acc[2][3];
    #pragma unroll
    for (int a_ = 0; a_ < 2; ++a_)
        #pragma unroll
        for (int b_ = 0; b_ < 3; ++b_)
            #pragma unroll
            for (int q = 0; q < 16; ++q) acc[a_][b_][q] = 0.0f;

    const unsigned short* arow = &xs[mt2 * 32 + l31][lhi * 8];
    for (int jc = 0; jc < 24; ++jc) {
        f32x16 c0, c1;
        #pragma unroll
        for (int q = 0; q < 16; ++q) { c0[q] = 0.0f; c1[q] = 0.0f; }
        const unsigned short* bpa =
            W1s + ((size_t)((e * 96 + jc * 4 + nt2l) * 48)) * 512 + lane * 8;
        #pragma unroll
        for (int kf = 0; kf < 48; kf += 2) {
            bf16x8 a0 = *reinterpret_cast<const bf16x8*>(arow + kf * 16);
            bf16x8 b0 = *reinterpret_cast<const bf16x8*>(bpa + (size_t)kf * 512);
            c0 = MFMA32(a0, b0, c0);
            bf16x8 a1 = *reinterpret_cast<const bf16x8*>(arow + kf * 16 + 16);
            bf16x8 b1 = *reinterpret_cast<const bf16x8*>(bpa + (size_t)kf * 512 + 512);
            c1 = MFMA32(a1, b1, c1);
        }
        #pragma unroll
        for (int q = 0; q < 16; ++q) c0[q] += c1[q];
        {
            int colc = nt2l * 32 + l31;
            float bias = b1[e * HID + jc * 128 + colc];
            #pragma unroll
            for (int reg = 0; reg < 16; ++reg) {
                int row = (reg & 3) + 8 * (reg >> 2) + 4 * lhi;
                float v = c0[reg] + bias;
                float gl = 0.5f * v * (1.0f + erff(v * 0.70710678118654752f));
                hs[jc & 1][mt2 * 32 + row][colc] = f2bf(gl);
            }
        }
        __syncthreads();
        const unsigned short* bpb =
            W2s + ((size_t)((e * 24 + wv * 3) * 192 + jc * 8)) * 512 + lane * 8;
        #pragma unroll
        for (int kf = 0; kf < 8; ++kf) {
            bf16x8 af0 = *reinterpret_cast<const bf16x8*>(&hs[jc & 1][l31][kf * 16 + lhi * 8]);
            bf16x8 af1 = *reinterpret_cast<const bf16x8*>(&hs[jc & 1][32 + l31][kf * 16 + lhi * 8]);
            #pragma unroll
            for (int i = 0; i < 3; ++i) {
                bf16x8 bv = *reinterpret_cast<const bf16x8*>(bpb + ((size_t)i * 192 + kf) * 512);
                acc[0][i] = MFMA32(af0, bv, acc[0][i]);
                acc[1][i] = MFMA32(af1, bv, acc[1][i]);
            }
        }
    }
    #pragma unroll
    for (int mt = 0; mt < 2; ++mt) {
        #pragma unroll
        for (int i = 0; i < 3; ++i) {
            int cg = (wv * 3 + i) * 32 + l31;
            float bias2 = b2[e * DIM + cg];
            #pragma unroll
            for (int reg = 0; reg < 16; ++reg) {
                int row = mt * 32 + (reg & 3) + 8 * (reg >> 2) + 4 * lhi;
                float g = sg[row];
                if (g > 0.0f) {
                    float v = acc[mt][i][reg] + bias2;
                    atomicAdd(out + (size_t)st[row] * DIM + cg, g * expf(v));
                }
            }
        }
    }
}

// =====================================================================

extern "C" void kernel_launch(void* const* d_in, const int* in_sizes, int n_in,
                              void* d_out, int out_size, void* d_ws, size_t ws_size,
                              hipStream_t stream) {
    const float* x  = (const float*)d_in[0];
    const float* wg = (const float*)d_in[1];
    const float* W1 = (const float*)d_in[2];
    const float* b1 = (const float*)d_in[3];
    const float* W2 = (const float*)d_in[4];
    const float* b2 = (const float*)d_in[5];
    float* out = (float*)d_out;

    // workspace layout (round-0 proven)
    char* ws = (char*)d_ws;
    int*            counts = (int*)ws;                                   // 5*128B padded
    int*            btok   = (int*)(ws + 1024);                          // 320 KB
    float*          bgate  = (float*)(ws + 1024 + 327680);               // 320 KB
    unsigned short* xb     = (unsigned short*)(ws + 1024 + 2 * 327680);  // 24 MB
    unsigned short* W1b    = xb + (size_t)T_TOK * DIM;                   // 22.5 MB
    unsigned short* W2b    = W1b + (size_t)NE * DIM * HID;               // 22.5 MB
    unsigned short* h0     = W2b + (size_t)NE * HID * DIM;               // 48.75 MB
    unsigned short* h1     = h0 + (size_t)HCAP * HID;                    // 48.75 MB

    const size_t need_fast = 1024 + 2 * 327680
        + (size_t)T_TOK * DIM * 2 + 2 * (size_t)NE * DIM * HID * 2
        + 2 * (size_t)HCAP * HID * 2;
    const bool fast = ws_size >= need_fast;

    hipMemsetAsync(counts, 0, 1024, stream);
    hipMemsetAsync(out, 0, (size_t)out_size * sizeof(float), stream);

    gate_kernel<<<T_TOK / 64, 256, 0, stream>>>(x, wg, xb, counts, btok, bgate);

    if (fast) {
        prep_w1p<<<(NE * 24 * 12 * 128 * 8 + 255) / 256, 256, 0, stream>>>(W1, W1b);
        prep_w2p<<<(NE * 6 * 48 * 128 * 8 + 255) / 256, 256, 0, stream>>>(W2, W2b);
        const int gmax = (MT2 + 7) / 8;  // max 256-row m-groups on one XCD (=5)
        for (int s = 0; s < 6; ++s) {
            int g1e = (s <= 4) ? s : -1;
            int g2e = s - 1;
            // per-XCD job count (XCD 0 has the most groups); grid = 8 * that
            int per_x0 = (g2e >= 0 ? gmax * 6 : 0) + (g1e >= 0 ? gmax * 24 : 0);
            combo_w<<<NXCD * per_x0, 512, 0, stream>>>(
                xb, W1b, W2b, b1, b2, counts, btok, bgate, h0, h1, out, g1e, g2e);
        }
    } else {
        prep_w1_v2<<<NE * 96 * 48 / 4, 256, 0, stream>>>(W1, W1b);
        prep_w2_v2<<<NE * 24 * 192 / 4, 256, 0, stream>>>(W2, W2b);
        expert_v2<<<dim3(T_TOK / 64, NE), 512, 0, stream>>>(
            xb, W1b, W2b, b1, b2, counts, btok, bgate, out);
    }

    log_kernel<<<(out_size / 4 + 255) / 256, 256, 0, stream>>>(out, out_size / 4);
}

// Round 10
// 810.903 us; speedup vs baseline: 1.1659x; 1.1659x over previous
//
#include <hip/hip_runtime.h>
#include <math.h>

// Problem constants (from reference)
#define T_TOK 16384
#define DIM   768
#define HID   3072
#define NE    5
#define MT    65            // max 128-row m-tiles per expert bucket (cap 8320 rows)
#define HCAP  (MT * 128)
#define CSTR  32            // counts stride (ints) -> one 128B line per expert
#define EPSF  2.2204460492503131e-16f
#define NXCD  8

typedef short bf16x8  __attribute__((ext_vector_type(8)));   // 8 bf16 in 4 VGPRs
typedef float f32x4   __attribute__((ext_vector_type(4)));
typedef float f32x16  __attribute__((ext_vector_type(16)));

#define MFMA16(A, B, C) __builtin_amdgcn_mfma_f32_16x16x32_bf16((A), (B), (C), 0, 0, 0)
#define MFMA32(A, B, C) __builtin_amdgcn_mfma_f32_32x32x16_bf16((A), (B), (C), 0, 0, 0)

__device__ __forceinline__ unsigned short f2bf(float f) {
    unsigned int u = __float_as_uint(f);
    unsigned int r = (u + 0x7fffu + ((u >> 16) & 1u)) >> 16;  // RNE
    return (unsigned short)r;
}

__device__ __forceinline__ void gld16(const void* g, void* l) {
    __builtin_amdgcn_global_load_lds(
        (const __attribute__((address_space(1))) void*)g,
        (__attribute__((address_space(3))) void*)l, 16, 0, 0);
}

// ---------------- prep: W1/W2 -> LDS-tile-linear, XOR-swizzled bf16 ----------------
// Coalesced rewrite of prep_w1p/prep_w2p (same output bytes): each block owns one
// 64(k) x 128(n) source tile. Reads: coalesced float4 along n. LDS transpose to the
// swizzled in-tile layout: ls[n*64 + ((r>>3)^(n&7))*8 + (r&7)]. Writes: the dest
// tile is CONTIGUOUS 16 KB (tile-linear layout), written as coalesced 16B stores.
// W1 tiles: t=(e*24+nb)*12+kb (1440). W2 tiles: t=(e*6+nb)*48+kb (1440). One launch.
__global__ __launch_bounds__(256) void prep_both(
    const float* __restrict__ W1, const float* __restrict__ W2,
    unsigned short* __restrict__ W1p, unsigned short* __restrict__ W2p) {
    __shared__ unsigned short ls[8192];   // 16 KB
    int b = blockIdx.x;
    const float* src; unsigned short* dst;
    int KBt, NBt, nrows, rowlen;
    if (b < 1440) { src = W1; dst = W1p; KBt = 12; NBt = 24; nrows = DIM; rowlen = HID; }
    else { b -= 1440; src = W2; dst = W2p; KBt = 48; NBt = 6; nrows = HID; rowlen = DIM; }
    const int kb = b % KBt;
    const int t2 = b / KBt;
    const int nb = t2 % NBt;
    const int e  = t2 / NBt;

    const int tid = threadIdx.x;
    const int r = tid >> 2, cg = tid & 3;       // row 0..63, col-group 0..3 (32 cols)
    const float* s = src + ((size_t)e * nrows + kb * 64 + r) * rowlen + nb * 128 + cg * 32;
    const int p8 = ((r >> 3) << 3);             // p' * 8 pre-xor
    const int j  = r & 7;
    #pragma unroll
    for (int i4 = 0; i4 < 8; ++i4) {
        float4 v = *reinterpret_cast<const float4*>(s + i4 * 4);
        int n0 = cg * 32 + i4 * 4;
        #pragma unroll
        for (int jj = 0; jj < 4; ++jj) {
            int n = n0 + jj;
            ls[n * 64 + (p8 ^ ((n & 7) << 3)) + j] = f2bf((&v.x)[jj]);
        }
    }
    __syncthreads();
    unsigned short* o = dst + (size_t)b * 8192;
    #pragma unroll
    for (int q = 0; q < 4; ++q)
        *reinterpret_cast<bf16x8*>(o + q * 2048 + tid * 8) =
            *reinterpret_cast<const bf16x8*>(ls + q * 2048 + tid * 8);
}

// ---------------- gating + x cast, block-aggregated scatter ----------------
__global__ __launch_bounds__(256) void gate_kernel(
    const float* __restrict__ x, const float* __restrict__ wg,
    unsigned short* __restrict__ xb, int* __restrict__ counts,
    int* __restrict__ btok, float* __restrict__ bgate) {
    __shared__ int   s_e[2][64];
    __shared__ float s_g[2][64];
    __shared__ int   lcnt[NE];
    __shared__ int   gbase[NE];

    const int tid = threadIdx.x;
    if (tid < NE) lcnt[tid] = 0;
    const int grp = tid >> 4, l16 = tid & 15;
    const int t0 = blockIdx.x * 64 + grp * 4;   // 4 consecutive tokens per group

    double acc[4][NE];
    #pragma unroll
    for (int tt = 0; tt < 4; ++tt)
        #pragma unroll
        for (int e = 0; e < NE; ++e) acc[tt][e] = 0.0;

    for (int i = 0; i < 12; ++i) {
        const int dbase = i * 64 + l16 * 4;
        float4 xv[4];
        #pragma unroll
        for (int tt = 0; tt < 4; ++tt) {
            xv[tt] = *reinterpret_cast<const float4*>(x + (size_t)(t0 + tt) * DIM + dbase);
            ushort4 o;
            o.x = f2bf(xv[tt].x); o.y = f2bf(xv[tt].y);
            o.z = f2bf(xv[tt].z); o.w = f2bf(xv[tt].w);
            *reinterpret_cast<ushort4*>(xb + (size_t)(t0 + tt) * DIM + dbase) = o;
        }
        #pragma unroll
        for (int j = 0; j < 4; ++j) {
            const int d = dbase + j;
            float w0 = wg[d * NE + 0], w1 = wg[d * NE + 1], w2 = wg[d * NE + 2];
            float w3 = wg[d * NE + 3], w4 = wg[d * NE + 4];
            #pragma unroll
            for (int tt = 0; tt < 4; ++tt) {
                double xd = (double)((&xv[tt].x)[j]);
                acc[tt][0] += xd * (double)w0;
                acc[tt][1] += xd * (double)w1;
                acc[tt][2] += xd * (double)w2;
                acc[tt][3] += xd * (double)w3;
                acc[tt][4] += xd * (double)w4;
            }
        }
    }
    #pragma unroll
    for (int off = 8; off; off >>= 1)
        #pragma unroll
        for (int tt = 0; tt < 4; ++tt)
            #pragma unroll
            for (int e = 0; e < NE; ++e)
                acc[tt][e] += __shfl_down(acc[tt][e], off, 16);

    if (l16 == 0) {
        #pragma unroll
        for (int tt = 0; tt < 4; ++tt) {
            double v[NE] = {acc[tt][0], acc[tt][1], acc[tt][2], acc[tt][3], acc[tt][4]};
            int i0 = 0;
            for (int e = 1; e < NE; ++e) if (v[e] > v[i0]) i0 = e;
            int i1 = -1;
            for (int e = 0; e < NE; ++e) {
                if (e == i0) continue;
                if (i1 < 0 || v[e] > v[i1]) i1 = e;
            }
            float e1 = expf((float)(v[i1] - v[i0]));
            float g0 = 1.0f / (1.0f + e1);
            int li = grp * 4 + tt;
            s_e[0][li] = i0;  s_g[0][li] = g0;
            s_e[1][li] = i1;  s_g[1][li] = e1 * g0;
        }
    }
    __syncthreads();

    int mye = 0, myoff = 0, mytok = 0;
    float myg = 0.0f;
    if (tid < 128) {
        int li = tid >> 1, which = tid & 1;
        mye = s_e[which][li];
        myg = s_g[which][li];
        mytok = blockIdx.x * 64 + li;
        myoff = atomicAdd(&lcnt[mye], 1);
    }
    __syncthreads();
    if (tid < NE) gbase[tid] = atomicAdd(&counts[tid * CSTR], lcnt[tid]);
    __syncthreads();
    if (tid < 128) {
        int p = gbase[mye] + myoff;
        btok[mye * T_TOK + p] = mytok;
        bgate[mye * T_TOK + p] = myg;
    }
}

// ---------------- combo GEMM kernel (round-8 proven: 128x128, 4 blocks/CU) --------
__global__ __launch_bounds__(256, 4) void combo_kernel(
    const unsigned short* __restrict__ xb,
    const unsigned short* __restrict__ W1p,
    const unsigned short* __restrict__ W2p,
    const float* __restrict__ b1, const float* __restrict__ b2,
    const int* __restrict__ counts, const int* __restrict__ btok,
    const float* __restrict__ bgate,
    unsigned short* __restrict__ h0, unsigned short* __restrict__ h1,
    float* __restrict__ out, int g1e, int g2e) {
    __shared__ __align__(16) unsigned short As[128 * 64];   // 16 KB
    __shared__ __align__(16) unsigned short Bs[128 * 64];   // 16 KB
    __shared__ int   sst[128];
    __shared__ float ssg[128];

    // ---- XCD-chunked, long-job-first decode (round-3, -42% FETCH) ----
    const int x = blockIdx.x & 7;        // XCD id (HW round-robins consecutive bx)
    const int i = blockIdx.x >> 3;       // per-XCD job index
    const int NG2 = (g2e >= 0) ? MT : 0;
    const int NG1 = (g1e >= 0) ? MT : 0;
    const int n2x = (x < NG2) ? (((NG2 - 1 - x) >> 3) + 1) : 0;
    const int n1x = (x < NG1) ? (((NG1 - 1 - x) >> 3) + 1) : 0;
    bool isG2; int e, mt, nt;
    if (i < n2x * 6) {
        isG2 = true;  e = g2e; mt = x + 8 * (i / 6);  nt = i % 6;
    } else {
        int ii = i - n2x * 6;
        if (ii >= n1x * 24) return;      // padded block
        isG2 = false; e = g1e; mt = x + 8 * (ii / 24); nt = ii % 24;
    }
    const int cnt = counts[e * CSTR];
    const int m0 = mt * 128;
    if (m0 >= cnt) return;
    unsigned short* hbuf = (e & 1) ? h1 : h0;  // parity ping-pong (g1e=g2e+1 -> disjoint)

    const int tid = threadIdx.x;
    const int wv = tid >> 6, lane = tid & 63;
    const int wm = wv >> 1, wn = wv & 1;
    const int col = lane & 15, quad = lane >> 4;
    const int l8 = lane & 7, r8 = lane >> 3;

    const unsigned short* aptr[4];
    if (isG2) {
        if (tid < 128) {
            int pos = m0 + tid;
            sst[tid] = (pos < cnt) ? btok[e * T_TOK + pos] : 0;
            ssg[tid] = (pos < cnt) ? bgate[e * T_TOK + pos] : 0.0f;
        }
        #pragma unroll
        for (int q = 0; q < 4; ++q) {
            int r = wv * 32 + q * 8 + r8;
            aptr[q] = hbuf + (size_t)(m0 + r) * HID + (l8 ^ r8) * 8;
        }
    } else {
        #pragma unroll
        for (int q = 0; q < 4; ++q) {
            int r = wv * 32 + q * 8 + r8;
            int pos = m0 + r;
            int tok = btok[e * T_TOK + (pos < cnt ? pos : 0)];
            aptr[q] = xb + (size_t)tok * DIM + (l8 ^ r8) * 8;
        }
    }
    const unsigned short* btile = isG2
        ? W2p + ((size_t)(e * 6 + nt)) * 48 * 8192
        : W1p + ((size_t)(e * 24 + nt)) * 12 * 8192;
    const int ksteps = isG2 ? 48 : 12;

    f32x4 acc[4][4];
    #pragma unroll
    for (int i2 = 0; i2 < 4; ++i2)
        #pragma unroll
        for (int j = 0; j < 4; ++j)
            acc[i2][j] = (f32x4){0.f, 0.f, 0.f, 0.f};

    for (int ks = 0; ks < ksteps; ++ks) {
        const unsigned short* bk = btile + (size_t)ks * 8192 + (size_t)wv * 2048 + lane * 8;
        #pragma unroll
        for (int q = 0; q < 4; ++q)
            gld16(aptr[q] + ks * 64, &As[(wv * 4 + q) * 512]);
        #pragma unroll
        for (int q = 0; q < 4; ++q)
            gld16(bk + q * 512, &Bs[(wv * 4 + q) * 512]);
        __syncthreads();
        #pragma unroll
        for (int kf = 0; kf < 2; ++kf) {
            const int p = ((kf * 4 + quad) ^ l8) * 8;
            bf16x8 a[4], b[4];
            #pragma unroll
            for (int i2 = 0; i2 < 4; ++i2)
                a[i2] = *reinterpret_cast<const bf16x8*>(&As[(wm * 64 + i2 * 16 + col) * 64 + p]);
            #pragma unroll
            for (int i2 = 0; i2 < 4; ++i2)
                b[i2] = *reinterpret_cast<const bf16x8*>(&Bs[(wn * 64 + i2 * 16 + col) * 64 + p]);
            #pragma unroll
            for (int i2 = 0; i2 < 4; ++i2)
                #pragma unroll
                for (int j = 0; j < 4; ++j)
                    acc[i2][j] = MFMA16(a[i2], b[j], acc[i2][j]);
        }
        __syncthreads();
    }

    const int nb0 = nt * 128 + wn * 64;
    if (!isG2) {
        #pragma unroll
        for (int j = 0; j < 4; ++j) {
            float bias = b1[e * HID + nb0 + j * 16 + col];
            #pragma unroll
            for (int i2 = 0; i2 < 4; ++i2) {
                #pragma unroll
                for (int r = 0; r < 4; ++r) {
                    int row = m0 + wm * 64 + i2 * 16 + quad * 4 + r;
                    float v = acc[i2][j][r] + bias;
                    float gl = 0.5f * v * (1.0f + erff(v * 0.70710678118654752f));
                    hbuf[(size_t)row * HID + nb0 + j * 16 + col] = f2bf(gl);
                }
            }
        }
    } else {
        #pragma unroll
        for (int j = 0; j < 4; ++j) {
            float bias = b2[e * DIM + nb0 + j * 16 + col];
            #pragma unroll
            for (int i2 = 0; i2 < 4; ++i2) {
                #pragma unroll
                for (int r = 0; r < 4; ++r) {
                    int lrow = wm * 64 + i2 * 16 + quad * 4 + r;
                    float g = ssg[lrow];
                    if (g > 0.0f) {
                        float v = acc[i2][j][r] + bias;
                        atomicAdd(out + (size_t)sst[lrow] * DIM + nb0 + j * 16 + col,
                                  g * expf(v));
                    }
                }
            }
        }
    }
}

// ---------------- final: out = log(acc), eps guard (float4) ----------------
__global__ void log_kernel(float* __restrict__ out, int n4) {
    int i = blockIdx.x * 256 + threadIdx.x;
    if (i < n4) {
        float4 v = reinterpret_cast<float4*>(out)[i];
        v.x = logf(v.x == 0.0f ? EPSF : v.x);
        v.y = logf(v.y == 0.0f ? EPSF : v.y);
        v.z = logf(v.z == 0.0f ? EPSF : v.z);
        v.w = logf(v.w == 0.0f ? EPSF : v.w);
        reinterpret_cast<float4*>(out)[i] = v;
    }
}

// ================= fallback path (used only if ws too small) =================
__global__ void prep_w1_v2(const float* __restrict__ W1, unsigned short* __restrict__ W1s) {
    int g = blockIdx.x * 4 + (threadIdx.x >> 6);
    int lane = threadIdx.x & 63;
    int kf = g % 48;
    int rest = g / 48;
    int nt2 = rest % 96;
    int e = rest / 96;
    int n = nt2 * 32 + (lane & 31);
    int k0 = kf * 16 + (lane >> 5) * 8;
    const float* src = W1 + ((size_t)e * DIM + k0) * HID + n;
    bf16x8 v;
    #pragma unroll
    for (int j = 0; j < 8; ++j) v[j] = (short)f2bf(src[(size_t)j * HID]);
    *reinterpret_cast<bf16x8*>(W1s + ((size_t)g * 64 + lane) * 8) = v;
}

__global__ void prep_w2_v2(const float* __restrict__ W2, unsigned short* __restrict__ W2s) {
    int g = blockIdx.x * 4 + (threadIdx.x >> 6);
    int lane = threadIdx.x & 63;
    int kf = g % 192;
    int rest = g / 192;
    int nt2 = rest % 24;
    int e = rest / 24;
    int n = nt2 * 32 + (lane & 31);
    int k0 = kf * 16 + (lane >> 5) * 8;
    const float* src = W2 + ((size_t)e * HID + k0) * DIM + n;
    bf16x8 v;
    #pragma unroll
    for (int j = 0; j < 8; ++j) v[j] = (short)f2bf(src[(size_t)j * DIM]);
    *reinterpret_cast<bf16x8*>(W2s + ((size_t)g * 64 + lane) * 8) = v;
}

__global__ __launch_bounds__(512, 2) void expert_v2(
    const unsigned short* __restrict__ xb, const unsigned short* __restrict__ W1s,
    const unsigned short* __restrict__ W2s, const float* __restrict__ b1,
    const float* __restrict__ b2, const int* __restrict__ counts,
    const int* __restrict__ btok, const float* __restrict__ bgate,
    float* __restrict__ out) {
    __shared__ __align__(16) unsigned short xs[64][776];
    __shared__ __align__(16) unsigned short hs[2][64][136];
    __shared__ int   st[64];
    __shared__ float sg[64];

    const int e = blockIdx.y;
    const int cnt = counts[e * CSTR];
    const int m0 = blockIdx.x * 64;
    if (m0 >= cnt) return;

    const int tid = threadIdx.x;
    const int wv = tid >> 6, lane = tid & 63;
    const int l31 = lane & 31, lhi = lane >> 5;

    if (tid < 64) {
        int pos = m0 + tid;
        st[tid] = (pos < cnt) ? btok[e * T_TOK + pos] : 0;
        sg[tid] = (pos < cnt) ? bgate[e * T_TOK + pos] : 0.0f;
    }
    __syncthreads();
    {
        int r = tid >> 3, seg = tid & 7;
        const unsigned short* src = xb + (size_t)st[r] * DIM + seg * 96;
        unsigned short* dst = &xs[r][seg * 96];
        #pragma unroll
        for (int i = 0; i < 12; ++i)
            reinterpret_cast<bf16x8*>(dst)[i] = reinterpret_cast<const bf16x8*>(src)[i];
    }
    __syncthreads();

    const int mt2 = wv & 1, nt2l = wv >> 1;
    f32x16 acc[2][3];
    #pragma unroll
    for (int a_ = 0; a_ < 2; ++a_)
        #pragma unroll
        for (int b_ = 0; b_ < 3; ++b_)
            #pragma unroll
            for (int q = 0; q < 16; ++q) acc[a_][b_][q] = 0.0f;

    const unsigned short* arow = &xs[mt2 * 32 + l31][lhi * 8];
    for (int jc = 0; jc < 24; ++jc) {
        f32x16 c0, c1;
        #pragma unroll
        for (int q = 0; q < 16; ++q) { c0[q] = 0.0f; c1[q] = 0.0f; }
        const unsigned short* bpa =
            W1s + ((size_t)((e * 96 + jc * 4 + nt2l) * 48)) * 512 + lane * 8;
        #pragma unroll
        for (int kf = 0; kf < 48; kf += 2) {
            bf16x8 a0 = *reinterpret_cast<const bf16x8*>(arow + kf * 16);
            bf16x8 b0 = *reinterpret_cast<const bf16x8*>(bpa + (size_t)kf * 512);
            c0 = MFMA32(a0, b0, c0);
            bf16x8 a1 = *reinterpret_cast<const bf16x8*>(arow + kf * 16 + 16);
            bf16x8 b1 = *reinterpret_cast<const bf16x8*>(bpa + (size_t)kf * 512 + 512);
            c1 = MFMA32(a1, b1, c1);
        }
        #pragma unroll
        for (int q = 0; q < 16; ++q) c0[q] += c1[q];
        {
            int colc = nt2l * 32 + l31;
            float bias = b1[e * HID + jc * 128 + colc];
            #pragma unroll
            for (int reg = 0; reg < 16; ++reg) {
                int row = (reg & 3) + 8 * (reg >> 2) + 4 * lhi;
                float v = c0[reg] + bias;
                float gl = 0.5f * v * (1.0f + erff(v * 0.70710678118654752f));
                hs[jc & 1][mt2 * 32 + row][colc] = f2bf(gl);
            }
        }
        __syncthreads();
        const unsigned short* bpb =
            W2s + ((size_t)((e * 24 + wv * 3) * 192 + jc * 8)) * 512 + lane * 8;
        #pragma unroll
        for (int kf = 0; kf < 8; ++kf) {
            bf16x8 af0 = *reinterpret_cast<const bf16x8*>(&hs[jc & 1][l31][kf * 16 + lhi * 8]);
            bf16x8 af1 = *reinterpret_cast<const bf16x8*>(&hs[jc & 1][32 + l31][kf * 16 + lhi * 8]);
            #pragma unroll
            for (int i = 0; i < 3; ++i) {
                bf16x8 bv = *reinterpret_cast<const bf16x8*>(bpb + ((size_t)i * 192 + kf) * 512);
                acc[0][i] = MFMA32(af0, bv, acc[0][i]);
                acc[1][i] = MFMA32(af1, bv, acc[1][i]);
            }
        }
    }
    #pragma unroll
    for (int mt = 0; mt < 2; ++mt) {
        #pragma unroll
        for (int i = 0; i < 3; ++i) {
            int cg = (wv * 3 + i) * 32 + l31;
            float bias2 = b2[e * DIM + cg];
            #pragma unroll
            for (int reg = 0; reg < 16; ++reg) {
                int row = mt * 32 + (reg & 3) + 8 * (reg >> 2) + 4 * lhi;
                float g = sg[row];
                if (g > 0.0f) {
                    float v = acc[mt][i][reg] + bias2;
                    atomicAdd(out + (size_t)st[row] * DIM + cg, g * expf(v));
                }
            }
        }
    }
}

// =====================================================================

extern "C" void kernel_launch(void* const* d_in, const int* in_sizes, int n_in,
                              void* d_out, int out_size, void* d_ws, size_t ws_size,
                              hipStream_t stream) {
    const float* x  = (const float*)d_in[0];
    const float* wg = (const float*)d_in[1];
    const float* W1 = (const float*)d_in[2];
    const float* b1 = (const float*)d_in[3];
    const float* W2 = (const float*)d_in[4];
    const float* b2 = (const float*)d_in[5];
    float* out = (float*)d_out;

    // workspace layout (round-0 proven)
    char* ws = (char*)d_ws;
    int*            counts = (int*)ws;                                   // 5*128B padded
    int*            btok   = (int*)(ws + 1024);                          // 320 KB
    float*          bgate  = (float*)(ws + 1024 + 327680);               // 320 KB
    unsigned short* xb     = (unsigned short*)(ws + 1024 + 2 * 327680);  // 24 MB
    unsigned short* W1b    = xb + (size_t)T_TOK * DIM;                   // 22.5 MB
    unsigned short* W2b    = W1b + (size_t)NE * DIM * HID;               // 22.5 MB
    unsigned short* h0     = W2b + (size_t)NE * HID * DIM;               // 48.75 MB
    unsigned short* h1     = h0 + (size_t)HCAP * HID;                    // 48.75 MB

    const size_t need_fast = 1024 + 2 * 327680
        + (size_t)T_TOK * DIM * 2 + 2 * (size_t)NE * DIM * HID * 2
        + 2 * (size_t)HCAP * HID * 2;
    const bool fast = ws_size >= need_fast;

    hipMemsetAsync(counts, 0, 1024, stream);
    hipMemsetAsync(out, 0, (size_t)out_size * sizeof(float), stream);

    gate_kernel<<<T_TOK / 64, 256, 0, stream>>>(x, wg, xb, counts, btok, bgate);

    if (fast) {
        prep_both<<<2880, 256, 0, stream>>>(W1, W2, W1b, W2b);
        const int gmax = (MT + 7) / 8;   // max m-tile groups on one XCD (=9)
        for (int s = 0; s < 6; ++s) {
            int g1e = (s <= 4) ? s : -1;
            int g2e = s - 1;
            // per-XCD job count (XCD 0 has the most groups); grid = 8 * that
            int per_x0 = (g2e >= 0 ? gmax * 6 : 0) + (g1e >= 0 ? gmax * 24 : 0);
            combo_kernel<<<NXCD * per_x0, 256, 0, stream>>>(
                xb, W1b, W2b, b1, b2, counts, btok, bgate, h0, h1, out, g1e, g2e);
        }
    } else {
        prep_w1_v2<<<NE * 96 * 48 / 4, 256, 0, stream>>>(W1, W1b);
        prep_w2_v2<<<NE * 24 * 192 / 4, 256, 0, stream>>>(W2, W2b);
        expert_v2<<<dim3(T_TOK / 64, NE), 512, 0, stream>>>(
            xb, W1b, W2b, b1, b2, counts, btok, bgate, out);
    }

    log_kernel<<<(out_size / 4 + 255) / 256, 256, 0, stream>>>(out, out_size / 4);
}

// Round 11
// 702.589 us; speedup vs baseline: 1.3457x; 1.1542x over previous
//
#include <hip/hip_runtime.h>
#include <math.h>

// Problem constants (from reference)
#define T_TOK 16384
#define DIM   768
#define HID   3072
#define NE    5
#define MT    65            // max 128-row m-tiles per expert bucket (cap 8320 rows)
#define HCAP  (MT * 128)
#define CSTR  32            // counts stride (ints) -> one 128B line per expert
#define EPSF  2.2204460492503131e-16f
#define NXCD  8

typedef short bf16x8  __attribute__((ext_vector_type(8)));   // 8 bf16 in 4 VGPRs
typedef float f32x4   __attribute__((ext_vector_type(4)));
typedef float f32x16  __attribute__((ext_vector_type(16)));

#define MFMA16(A, B, C) __builtin_amdgcn_mfma_f32_16x16x32_bf16((A), (B), (C), 0, 0, 0)
#define MFMA32(A, B, C) __builtin_amdgcn_mfma_f32_32x32x16_bf16((A), (B), (C), 0, 0, 0)

__device__ __forceinline__ unsigned short f2bf(float f) {
    unsigned int u = __float_as_uint(f);
    unsigned int r = (u + 0x7fffu + ((u >> 16) & 1u)) >> 16;  // RNE
    return (unsigned short)r;
}

__device__ __forceinline__ void gld16(const void* g, void* l) {
    __builtin_amdgcn_global_load_lds(
        (const __attribute__((address_space(1))) void*)g,
        (__attribute__((address_space(3))) void*)l, 16, 0, 0);
}

// ---------------- prep: W1 -> LDS-tile-linear, XOR-swizzled bf16 (round-8 proven) --
__global__ void prep_w1p(const float* __restrict__ W1, unsigned short* __restrict__ W1p) {
    int idx = blockIdx.x * 256 + threadIdx.x;
    if (idx >= NE * 24 * 12 * 128 * 8) return;
    int p = idx & 7;
    int n = (idx >> 3) & 127;
    int t = idx >> 10;
    int kb = t % 12; t /= 12;
    int nb = t % 24; int e = t / 24;
    int klog = kb * 64 + (p ^ (n & 7)) * 8;
    const float* src = W1 + ((size_t)e * DIM + klog) * HID + nb * 128 + n;
    bf16x8 v;
    #pragma unroll
    for (int j = 0; j < 8; ++j) v[j] = (short)f2bf(src[(size_t)j * HID]);
    *reinterpret_cast<bf16x8*>(W1p + (size_t)idx * 8) = v;
}

__global__ void prep_w2p(const float* __restrict__ W2, unsigned short* __restrict__ W2p) {
    int idx = blockIdx.x * 256 + threadIdx.x;
    if (idx >= NE * 6 * 48 * 128 * 8) return;
    int p = idx & 7;
    int n = (idx >> 3) & 127;
    int t = idx >> 10;
    int kb = t % 48; t /= 48;
    int nb = t % 6; int e = t / 6;
    int klog = kb * 64 + (p ^ (n & 7)) * 8;
    const float* src = W2 + ((size_t)e * HID + klog) * DIM + nb * 128 + n;
    bf16x8 v;
    #pragma unroll
    for (int j = 0; j < 8; ++j) v[j] = (short)f2bf(src[(size_t)j * DIM]);
    *reinterpret_cast<bf16x8*>(W2p + (size_t)idx * 8) = v;
}

// ---------------- gating + x cast, block-aggregated scatter ----------------
// bgate now carries the top-k SLOT in its sign bit: slot0 -> +g, slot1 -> -g.
// Consumers decode g = fabsf(bgate), slot = signbit.
__global__ __launch_bounds__(256) void gate_kernel(
    const float* __restrict__ x, const float* __restrict__ wg,
    unsigned short* __restrict__ xb, int* __restrict__ counts,
    int* __restrict__ btok, float* __restrict__ bgate) {
    __shared__ int   s_e[2][64];
    __shared__ float s_g[2][64];
    __shared__ int   lcnt[NE];
    __shared__ int   gbase[NE];

    const int tid = threadIdx.x;
    if (tid < NE) lcnt[tid] = 0;
    const int grp = tid >> 4, l16 = tid & 15;
    const int t0 = blockIdx.x * 64 + grp * 4;   // 4 consecutive tokens per group

    double acc[4][NE];
    #pragma unroll
    for (int tt = 0; tt < 4; ++tt)
        #pragma unroll
        for (int e = 0; e < NE; ++e) acc[tt][e] = 0.0;

    for (int i = 0; i < 12; ++i) {
        const int dbase = i * 64 + l16 * 4;
        float4 xv[4];
        #pragma unroll
        for (int tt = 0; tt < 4; ++tt) {
            xv[tt] = *reinterpret_cast<const float4*>(x + (size_t)(t0 + tt) * DIM + dbase);
            ushort4 o;
            o.x = f2bf(xv[tt].x); o.y = f2bf(xv[tt].y);
            o.z = f2bf(xv[tt].z); o.w = f2bf(xv[tt].w);
            *reinterpret_cast<ushort4*>(xb + (size_t)(t0 + tt) * DIM + dbase) = o;
        }
        #pragma unroll
        for (int j = 0; j < 4; ++j) {
            const int d = dbase + j;
            float w0 = wg[d * NE + 0], w1 = wg[d * NE + 1], w2 = wg[d * NE + 2];
            float w3 = wg[d * NE + 3], w4 = wg[d * NE + 4];
            #pragma unroll
            for (int tt = 0; tt < 4; ++tt) {
                double xd = (double)((&xv[tt].x)[j]);
                acc[tt][0] += xd * (double)w0;
                acc[tt][1] += xd * (double)w1;
                acc[tt][2] += xd * (double)w2;
                acc[tt][3] += xd * (double)w3;
                acc[tt][4] += xd * (double)w4;
            }
        }
    }
    #pragma unroll
    for (int off = 8; off; off >>= 1)
        #pragma unroll
        for (int tt = 0; tt < 4; ++tt)
            #pragma unroll
            for (int e = 0; e < NE; ++e)
                acc[tt][e] += __shfl_down(acc[tt][e], off, 16);

    if (l16 == 0) {
        #pragma unroll
        for (int tt = 0; tt < 4; ++tt) {
            double v[NE] = {acc[tt][0], acc[tt][1], acc[tt][2], acc[tt][3], acc[tt][4]};
            int i0 = 0;
            for (int e = 1; e < NE; ++e) if (v[e] > v[i0]) i0 = e;
            int i1 = -1;
            for (int e = 0; e < NE; ++e) {
                if (e == i0) continue;
                if (i1 < 0 || v[e] > v[i1]) i1 = e;
            }
            float e1 = expf((float)(v[i1] - v[i0]));
            float g0 = 1.0f / (1.0f + e1);
            int li = grp * 4 + tt;
            s_e[0][li] = i0;  s_g[0][li] = g0;
            s_e[1][li] = i1;  s_g[1][li] = -(e1 * g0);   // slot1 encoded negative
        }
    }
    __syncthreads();

    int mye = 0, myoff = 0, mytok = 0;
    float myg = 0.0f;
    if (tid < 128) {
        int li = tid >> 1, which = tid & 1;
        mye = s_e[which][li];
        myg = s_g[which][li];
        mytok = blockIdx.x * 64 + li;
        myoff = atomicAdd(&lcnt[mye], 1);
    }
    __syncthreads();
    if (tid < NE) gbase[tid] = atomicAdd(&counts[tid * CSTR], lcnt[tid]);
    __syncthreads();
    if (tid < 128) {
        int p = gbase[mye] + myoff;
        btok[mye * T_TOK + p] = mytok;
        bgate[mye * T_TOK + p] = myg;
    }
}

// ---------------- combo GEMM kernel (round-8 proven body; slot-split epilogue) ----
// p1 != nullptr  -> store mode: G2 writes g*exp(v) with PLAIN stores, slot0 -> out,
//   slot1 -> p1 (each (token,slot,col) written exactly once; no memset needed).
// p1 == nullptr  -> round-8 atomic mode (out pre-zeroed).
__global__ __launch_bounds__(256, 4) void combo_kernel(
    const unsigned short* __restrict__ xb,
    const unsigned short* __restrict__ W1p,
    const unsigned short* __restrict__ W2p,
    const float* __restrict__ b1, const float* __restrict__ b2,
    const int* __restrict__ counts, const int* __restrict__ btok,
    const float* __restrict__ bgate,
    unsigned short* __restrict__ h0, unsigned short* __restrict__ h1,
    float* __restrict__ out, float* __restrict__ p1, int g1e, int g2e) {
    __shared__ __align__(16) unsigned short As[128 * 64];   // 16 KB
    __shared__ __align__(16) unsigned short Bs[128 * 64];   // 16 KB
    __shared__ int   sst[128];
    __shared__ float ssg[128];

    // ---- XCD-chunked, long-job-first decode (round-3, -42% FETCH) ----
    const int x = blockIdx.x & 7;        // XCD id (HW round-robins consecutive bx)
    const int i = blockIdx.x >> 3;       // per-XCD job index
    const int NG2 = (g2e >= 0) ? MT : 0;
    const int NG1 = (g1e >= 0) ? MT : 0;
    const int n2x = (x < NG2) ? (((NG2 - 1 - x) >> 3) + 1) : 0;
    const int n1x = (x < NG1) ? (((NG1 - 1 - x) >> 3) + 1) : 0;
    bool isG2; int e, mt, nt;
    if (i < n2x * 6) {
        isG2 = true;  e = g2e; mt = x + 8 * (i / 6);  nt = i % 6;
    } else {
        int ii = i - n2x * 6;
        if (ii >= n1x * 24) return;      // padded block
        isG2 = false; e = g1e; mt = x + 8 * (ii / 24); nt = ii % 24;
    }
    const int cnt = counts[e * CSTR];
    const int m0 = mt * 128;
    if (m0 >= cnt) return;
    unsigned short* hbuf = (e & 1) ? h1 : h0;  // parity ping-pong (g1e=g2e+1 -> disjoint)

    const int tid = threadIdx.x;
    const int wv = tid >> 6, lane = tid & 63;
    const int wm = wv >> 1, wn = wv & 1;
    const int col = lane & 15, quad = lane >> 4;
    const int l8 = lane & 7, r8 = lane >> 3;

    const unsigned short* aptr[4];
    if (isG2) {
        if (tid < 128) {
            int pos = m0 + tid;
            sst[tid] = (pos < cnt) ? btok[e * T_TOK + pos] : -1;   // -1 = padding
            ssg[tid] = (pos < cnt) ? bgate[e * T_TOK + pos] : 0.0f;
        }
        #pragma unroll
        for (int q = 0; q < 4; ++q) {
            int r = wv * 32 + q * 8 + r8;
            aptr[q] = hbuf + (size_t)(m0 + r) * HID + (l8 ^ r8) * 8;
        }
    } else {
        #pragma unroll
        for (int q = 0; q < 4; ++q) {
            int r = wv * 32 + q * 8 + r8;
            int pos = m0 + r;
            int tok = btok[e * T_TOK + (pos < cnt ? pos : 0)];
            aptr[q] = xb + (size_t)tok * DIM + (l8 ^ r8) * 8;
        }
    }
    const unsigned short* btile = isG2
        ? W2p + ((size_t)(e * 6 + nt)) * 48 * 8192
        : W1p + ((size_t)(e * 24 + nt)) * 12 * 8192;
    const int ksteps = isG2 ? 48 : 12;

    f32x4 acc[4][4];
    #pragma unroll
    for (int i2 = 0; i2 < 4; ++i2)
        #pragma unroll
        for (int j = 0; j < 4; ++j)
            acc[i2][j] = (f32x4){0.f, 0.f, 0.f, 0.f};

    for (int ks = 0; ks < ksteps; ++ks) {
        const unsigned short* bk = btile + (size_t)ks * 8192 + (size_t)wv * 2048 + lane * 8;
        #pragma unroll
        for (int q = 0; q < 4; ++q)
            gld16(aptr[q] + ks * 64, &As[(wv * 4 + q) * 512]);
        #pragma unroll
        for (int q = 0; q < 4; ++q)
            gld16(bk + q * 512, &Bs[(wv * 4 + q) * 512]);
        __syncthreads();
        #pragma unroll
        for (int kf = 0; kf < 2; ++kf) {
            const int p = ((kf * 4 + quad) ^ l8) * 8;
            bf16x8 a[4], b[4];
            #pragma unroll
            for (int i2 = 0; i2 < 4; ++i2)
                a[i2] = *reinterpret_cast<const bf16x8*>(&As[(wm * 64 + i2 * 16 + col) * 64 + p]);
            #pragma unroll
            for (int i2 = 0; i2 < 4; ++i2)
                b[i2] = *reinterpret_cast<const bf16x8*>(&Bs[(wn * 64 + i2 * 16 + col) * 64 + p]);
            #pragma unroll
            for (int i2 = 0; i2 < 4; ++i2)
                #pragma unroll
                for (int j = 0; j < 4; ++j)
                    acc[i2][j] = MFMA16(a[i2], b[j], acc[i2][j]);
        }
        __syncthreads();
    }

    const int nb0 = nt * 128 + wn * 64;
    if (!isG2) {
        #pragma unroll
        for (int j = 0; j < 4; ++j) {
            float bias = b1[e * HID + nb0 + j * 16 + col];
            #pragma unroll
            for (int i2 = 0; i2 < 4; ++i2) {
                #pragma unroll
                for (int r = 0; r < 4; ++r) {
                    int row = m0 + wm * 64 + i2 * 16 + quad * 4 + r;
                    float v = acc[i2][j][r] + bias;
                    float gl = 0.5f * v * (1.0f + erff(v * 0.70710678118654752f));
                    hbuf[(size_t)row * HID + nb0 + j * 16 + col] = f2bf(gl);
                }
            }
        }
    } else {
        #pragma unroll
        for (int j = 0; j < 4; ++j) {
            float bias = b2[e * DIM + nb0 + j * 16 + col];
            #pragma unroll
            for (int i2 = 0; i2 < 4; ++i2) {
                #pragma unroll
                for (int r = 0; r < 4; ++r) {
                    int lrow = wm * 64 + i2 * 16 + quad * 4 + r;
                    int tok = sst[lrow];
                    if (tok >= 0) {
                        float graw = ssg[lrow];
                        float g = fabsf(graw);
                        float v = acc[i2][j][r] + bias;
                        size_t off = (size_t)tok * DIM + nb0 + j * 16 + col;
                        if (p1) {
                            // exactly-once plain store; 0 if gate underflowed
                            float val = (g > 0.0f) ? g * expf(v) : 0.0f;
                            float* dst = (__float_as_uint(graw) >> 31) ? p1 : out;
                            dst[off] = val;
                        } else if (g > 0.0f) {
                            atomicAdd(out + off, g * expf(v));
                        }
                    }
                }
            }
        }
    }
}

// ---------------- final passes ----------------
__global__ void log_kernel(float* __restrict__ out, int n4) {
    int i = blockIdx.x * 256 + threadIdx.x;
    if (i < n4) {
        float4 v = reinterpret_cast<float4*>(out)[i];
        v.x = logf(v.x == 0.0f ? EPSF : v.x);
        v.y = logf(v.y == 0.0f ? EPSF : v.y);
        v.z = logf(v.z == 0.0f ? EPSF : v.z);
        v.w = logf(v.w == 0.0f ? EPSF : v.w);
        reinterpret_cast<float4*>(out)[i] = v;
    }
}

// store mode: out = log(p0 + p1), eps guard on the SUM (matches reference acc==0)
__global__ void log2_kernel(float* __restrict__ out, const float* __restrict__ p1, int n4) {
    int i = blockIdx.x * 256 + threadIdx.x;
    if (i < n4) {
        float4 a = reinterpret_cast<float4*>(out)[i];
        float4 b = reinterpret_cast<const float4*>(p1)[i];
        float sx = a.x + b.x, sy = a.y + b.y, sz = a.z + b.z, sw = a.w + b.w;
        a.x = logf(sx == 0.0f ? EPSF : sx);
        a.y = logf(sy == 0.0f ? EPSF : sy);
        a.z = logf(sz == 0.0f ? EPSF : sz);
        a.w = logf(sw == 0.0f ? EPSF : sw);
        reinterpret_cast<float4*>(out)[i] = a;
    }
}

// ================= fallback path (used only if ws too small) =================
__global__ void prep_w1_v2(const float* __restrict__ W1, unsigned short* __restrict__ W1s) {
    int g = blockIdx.x * 4 + (threadIdx.x >> 6);
    int lane = threadIdx.x & 63;
    int kf = g % 48;
    int rest = g / 48;
    int nt2 = rest % 96;
    int e = rest / 96;
    int n = nt2 * 32 + (lane & 31);
    int k0 = kf * 16 + (lane >> 5) * 8;
    const float* src = W1 + ((size_t)e * DIM + k0) * HID + n;
    bf16x8 v;
    #pragma unroll
    for (int j = 0; j < 8; ++j) v[j] = (short)f2bf(src[(size_t)j * HID]);
    *reinterpret_cast<bf16x8*>(W1s + ((size_t)g * 64 + lane) * 8) = v;
}

__global__ void prep_w2_v2(const float* __restrict__ W2, unsigned short* __restrict__ W2s) {
    int g = blockIdx.x * 4 + (threadIdx.x >> 6);
    int lane = threadIdx.x & 63;
    int kf = g % 192;
    int rest = g / 192;
    int nt2 = rest % 24;
    int e = rest / 24;
    int n = nt2 * 32 + (lane & 31);
    int k0 = kf * 16 + (lane >> 5) * 8;
    const float* src = W2 + ((size_t)e * HID + k0) * DIM + n;
    bf16x8 v;
    #pragma unroll
    for (int j = 0; j < 8; ++j) v[j] = (short)f2bf(src[(size_t)j * DIM]);
    *reinterpret_cast<bf16x8*>(W2s + ((size_t)g * 64 + lane) * 8) = v;
}

__global__ __launch_bounds__(512, 2) void expert_v2(
    const unsigned short* __restrict__ xb, const unsigned short* __restrict__ W1s,
    const unsigned short* __restrict__ W2s, const float* __restrict__ b1,
    const float* __restrict__ b2, const int* __restrict__ counts,
    const int* __restrict__ btok, const float* __restrict__ bgate,
    float* __restrict__ out) {
    __shared__ __align__(16) unsigned short xs[64][776];
    __shared__ __align__(16) unsigned short hs[2][64][136];
    __shared__ int   st[64];
    __shared__ float sg[64];

    const int e = blockIdx.y;
    const int cnt = counts[e * CSTR];
    const int m0 = blockIdx.x * 64;
    if (m0 >= cnt) return;

    const int tid = threadIdx.x;
    const int wv = tid >> 6, lane = tid & 63;
    const int l31 = lane & 31, lhi = lane >> 5;

    if (tid < 64) {
        int pos = m0 + tid;
        st[tid] = (pos < cnt) ? btok[e * T_TOK + pos] : 0;
        sg[tid] = (pos < cnt) ? fabsf(bgate[e * T_TOK + pos]) : 0.0f;  // decode slot sign
    }
    __syncthreads();
    {
        int r = tid >> 3, seg = tid & 7;
        const unsigned short* src = xb + (size_t)st[r] * DIM + seg * 96;
        unsigned short* dst = &xs[r][seg * 96];
        #pragma unroll
        for (int i = 0; i < 12; ++i)
            reinterpret_cast<bf16x8*>(dst)[i] = reinterpret_cast<const bf16x8*>(src)[i];
    }
    __syncthreads();

    const int mt2 = wv & 1, nt2l = wv >> 1;
    f32x16 acc[2][3];
    #pragma unroll
    for (int a_ = 0; a_ < 2; ++a_)
        #pragma unroll
        for (int b_ = 0; b_ < 3; ++b_)
            #pragma unroll
            for (int q = 0; q < 16; ++q) acc[a_][b_][q] = 0.0f;

    const unsigned short* arow = &xs[mt2 * 32 + l31][lhi * 8];
    for (int jc = 0; jc < 24; ++jc) {
        f32x16 c0, c1;
        #pragma unroll
        for (int q = 0; q < 16; ++q) { c0[q] = 0.0f; c1[q] = 0.0f; }
        const unsigned short* bpa =
            W1s + ((size_t)((e * 96 + jc * 4 + nt2l) * 48)) * 512 + lane * 8;
        #pragma unroll
        for (int kf = 0; kf < 48; kf += 2) {
            bf16x8 a0 = *reinterpret_cast<const bf16x8*>(arow + kf * 16);
            bf16x8 b0 = *reinterpret_cast<const bf16x8*>(bpa + (size_t)kf * 512);
            c0 = MFMA32(a0, b0, c0);
            bf16x8 a1 = *reinterpret_cast<const bf16x8*>(arow + kf * 16 + 16);
            bf16x8 b1 = *reinterpret_cast<const bf16x8*>(bpa + (size_t)kf * 512 + 512);
            c1 = MFMA32(a1, b1, c1);
        }
        #pragma unroll
        for (int q = 0; q < 16; ++q) c0[q] += c1[q];
        {
            int colc = nt2l * 32 + l31;
            float bias = b1[e * HID + jc * 128 + colc];
            #pragma unroll
            for (int reg = 0; reg < 16; ++reg) {
                int row = (reg & 3) + 8 * (reg >> 2) + 4 * lhi;
                float v = c0[reg] + bias;
                float gl = 0.5f * v * (1.0f + erff(v * 0.70710678118654752f));
                hs[jc & 1][mt2 * 32 + row][colc] = f2bf(gl);
            }
        }
        __syncthreads();
        const unsigned short* bpb =
            W2s + ((size_t)((e * 24 + wv * 3) * 192 + jc * 8)) * 512 + lane * 8;
        #pragma unroll
        for (int kf = 0; kf < 8; ++kf) {
            bf16x8 af0 = *reinterpret_cast<const bf16x8*>(&hs[jc & 1][l31][kf * 16 + lhi * 8]);
            bf16x8 af1 = *reinterpret_cast<const bf16x8*>(&hs[jc & 1][32 + l31][kf * 16 + lhi * 8]);
            #pragma unroll
            for (int i = 0; i < 3; ++i) {
                bf16x8 bv = *reinterpret_cast<const bf16x8*>(bpb + ((size_t)i * 192 + kf) * 512);
                acc[0][i] = MFMA32(af0, bv, acc[0][i]);
                acc[1][i] = MFMA32(af1, bv, acc[1][i]);
            }
        }
    }
    #pragma unroll
    for (int mt = 0; mt < 2; ++mt) {
        #pragma unroll
        for (int i = 0; i < 3; ++i) {
            int cg = (wv * 3 + i) * 32 + l31;
            float bias2 = b2[e * DIM + cg];
            #pragma unroll
            for (int reg = 0; reg < 16; ++reg) {
                int row = mt * 32 + (reg & 3) + 8 * (reg >> 2) + 4 * lhi;
                float g = sg[row];
                if (g > 0.0f) {
                    float v = acc[mt][i][reg] + bias2;
                    atomicAdd(out + (size_t)st[row] * DIM + cg, g * expf(v));
                }
            }
        }
    }
}

// =====================================================================

extern "C" void kernel_launch(void* const* d_in, const int* in_sizes, int n_in,
                              void* d_out, int out_size, void* d_ws, size_t ws_size,
                              hipStream_t stream) {
    const float* x  = (const float*)d_in[0];
    const float* wg = (const float*)d_in[1];
    const float* W1 = (const float*)d_in[2];
    const float* b1 = (const float*)d_in[3];
    const float* W2 = (const float*)d_in[4];
    const float* b2 = (const float*)d_in[5];
    float* out = (float*)d_out;

    // workspace layout (round-0 proven) + optional p1 partial after h1
    char* ws = (char*)d_ws;
    int*            counts = (int*)ws;                                   // 5*128B padded
    int*            btok   = (int*)(ws + 1024);                          // 320 KB
    float*          bgate  = (float*)(ws + 1024 + 327680);               // 320 KB
    unsigned short* xb     = (unsigned short*)(ws + 1024 + 2 * 327680);  // 24 MB
    unsigned short* W1b    = xb + (size_t)T_TOK * DIM;                   // 22.5 MB
    unsigned short* W2b    = W1b + (size_t)NE * DIM * HID;               // 22.5 MB
    unsigned short* h0     = W2b + (size_t)NE * HID * DIM;               // 48.75 MB
    unsigned short* h1     = h0 + (size_t)HCAP * HID;                    // 48.75 MB
    float*          p1     = (float*)(h1 + (size_t)HCAP * HID);          // 50.3 MB (opt)

    const size_t need_fast = 1024 + 2 * 327680
        + (size_t)T_TOK * DIM * 2 + 2 * (size_t)NE * DIM * HID * 2
        + 2 * (size_t)HCAP * HID * 2;
    const size_t need_store = need_fast + (size_t)T_TOK * DIM * 4;
    const bool fast  = ws_size >= need_fast;
    const bool store = ws_size >= need_store;

    hipMemsetAsync(counts, 0, 1024, stream);
    if (!(fast && store))   // store mode needs no out zero-init (exactly-once stores)
        hipMemsetAsync(out, 0, (size_t)out_size * sizeof(float), stream);

    gate_kernel<<<T_TOK / 64, 256, 0, stream>>>(x, wg, xb, counts, btok, bgate);

    if (fast) {
        prep_w1p<<<(NE * 24 * 12 * 128 * 8 + 255) / 256, 256, 0, stream>>>(W1, W1b);
        prep_w2p<<<(NE * 6 * 48 * 128 * 8 + 255) / 256, 256, 0, stream>>>(W2, W2b);
        float* p1arg = store ? p1 : nullptr;
        const int gmax = (MT + 7) / 8;   // max m-tile groups on one XCD (=9)
        for (int s = 0; s < 6; ++s) {
            int g1e = (s <= 4) ? s : -1;
            int g2e = s - 1;
            int per_x0 = (g2e >= 0 ? gmax * 6 : 0) + (g1e >= 0 ? gmax * 24 : 0);
            combo_kernel<<<NXCD * per_x0, 256, 0, stream>>>(
                xb, W1b, W2b, b1, b2, counts, btok, bgate, h0, h1, out, p1arg, g1e, g2e);
        }
        if (store)
            log2_kernel<<<(out_size / 4 + 255) / 256, 256, 0, stream>>>(out, p1, out_size / 4);
        else
            log_kernel<<<(out_size / 4 + 255) / 256, 256, 0, stream>>>(out, out_size / 4);
    } else {
        prep_w1_v2<<<NE * 96 * 48 / 4, 256, 0, stream>>>(W1, W1b);
        prep_w2_v2<<<NE * 24 * 192 / 4, 256, 0, stream>>>(W2, W2b);
        expert_v2<<<dim3(T_TOK / 64, NE), 512, 0, stream>>>(
            xb, W1b, W2b, b1, b2, counts, btok, bgate, out);
        log_kernel<<<(out_size / 4 + 255) / 256, 256, 0, stream>>>(out, out_size / 4);
    }
}